// Round 6
// baseline (461.596 us; speedup 1.0000x reference)
//
#include <hip/hip_runtime.h>
#include <stdint.h>

// ---- problem constants ----
#define DIMX 1024
#define DIM_INNER 2048
#define BATCH 4
#define SEQ 4096
#define M_TOTAL (BATCH * SEQ)   // 16384
#define N_HG (2 * DIM_INNER)    // 4096
#define NCHUNK 256              // chunks along S (R6: 128->256 for 2x scan occupancy)
#define CLEN 16                 // steps per chunk (NCHUNK*CLEN == SEQ)

typedef unsigned short u16;
typedef __attribute__((ext_vector_type(8))) short short8;   // 8 x bf16 MFMA frag
typedef __attribute__((ext_vector_type(4))) float floatx4;  // MFMA acc

// ---- bf16 helpers (bit-level, RNE) ----
__device__ __forceinline__ float bflo(uint32_t u) { return __uint_as_float(u << 16); }
__device__ __forceinline__ float bfhi(uint32_t u) { return __uint_as_float(u & 0xffff0000u); }
__device__ __forceinline__ uint32_t f2bf_bits(float f) {
    uint32_t u = __float_as_uint(f);
    return (u + 0x7fffu + ((u >> 16) & 1u)) >> 16;  // round-to-nearest-even
}

// ============================================================
// prep kernel: fuses x-cast + Whg transpose + Wout transpose.
//   blocks [0,2048)            : cast x fp32 -> bf16 (grid-stride)
//   blocks [2048, 2048+1024)   : Whg  [1024][4096] -> whgt  [4096][1024] bf16
//   blocks [3072, 3072+512)    : Wout [2048][1024] -> woutt [1024][2048] bf16
// ============================================================
__global__ __launch_bounds__(256) void prep(const float* __restrict__ x,
                                            const float* __restrict__ Whg,
                                            const float* __restrict__ Wout,
                                            u16* __restrict__ xb,
                                            u16* __restrict__ whgt,
                                            u16* __restrict__ woutt) {
    __shared__ float tile[64][65];
    const int bid = blockIdx.x;
    const int tid = threadIdx.x;
    if (bid < 2048) {
        const int n4 = M_TOTAL * DIMX / 4;
        const float4* in4 = (const float4*)x;
        ushort4* out4 = (ushort4*)xb;
        for (int i = bid * 256 + tid; i < n4; i += 2048 * 256) {
            float4 v = in4[i];
            ushort4 o;
            o.x = (u16)f2bf_bits(v.x);
            o.y = (u16)f2bf_bits(v.y);
            o.z = (u16)f2bf_bits(v.z);
            o.w = (u16)f2bf_bits(v.w);
            out4[i] = o;
        }
        return;
    }
    const float* in;
    u16* out;
    int R, C, tb;
    if (bid < 3072) {
        in = Whg; out = whgt; R = DIMX; C = N_HG; tb = bid - 2048;
    } else {
        in = Wout; out = woutt; R = DIM_INNER; C = DIMX; tb = bid - 3072;
    }
    const int tilesx = C / 64;
    const int c0 = (tb % tilesx) * 64, r0 = (tb / tilesx) * 64;
    const int tx = tid & 63, ty = tid >> 6;  // 64 x 4
#pragma unroll
    for (int i = ty; i < 64; i += 4)
        tile[i][tx] = in[(size_t)(r0 + i) * C + c0 + tx];
    __syncthreads();
#pragma unroll
    for (int i = ty; i < 64; i += 4)
        out[(size_t)(c0 + i) * R + r0 + tx] = (u16)f2bf_bits(tile[tx][i]);
}

// ============================================================
// bf16 MFMA GEMM: C[M][N] = A[M][K] * B[K][N],  B given transposed as Bt[N][K].
// 128x128 block tile, BK=32, 256 threads (4 waves, each 64x64 = 4x4 MFMA tiles).
// global_load_lds width-16 staging + XOR k-block swizzle (R3: conflicts -> 0).
// ============================================================
template <int OUT_BF16>
__global__ __launch_bounds__(256, 2) void gemm_bf16(const u16* __restrict__ A,
                                                    const u16* __restrict__ Bt,
                                                    void* __restrict__ C,
                                                    const int M, const int N, const int K) {
    __shared__ alignas(16) u16 As[128 * 32];
    __shared__ alignas(16) u16 Bs[128 * 32];

    const int tid = threadIdx.x;
    const int lane = tid & 63;
    const int wave = tid >> 6;
    const int wm = (wave >> 1) * 64;
    const int wn = (wave & 1) * 64;
    const size_t m0 = (size_t)blockIdx.y * 128;
    const size_t n0 = (size_t)blockIdx.x * 128;

    floatx4 acc[4][4];
#pragma unroll
    for (int i = 0; i < 4; ++i)
#pragma unroll
        for (int j = 0; j < 4; ++j) acc[i][j] = (floatx4){0.f, 0.f, 0.f, 0.f};

    const int srow = lane >> 2;
    const int scol = ((lane & 3) ^ ((srow >> 1) & 3)) * 8;
    const u16* Ag = A + m0 * K + (size_t)(wave * 16 + srow) * K + scol;
    const u16* Bg = Bt + n0 * K + (size_t)(wave * 16 + srow) * K + scol;
    u16* Asw = As + (wave * 16) * 32;
    u16* Bsw = Bs + (wave * 16) * 32;

    const int fr = lane & 15;
    const int kblk = lane >> 4;
    const int koff = (kblk ^ ((fr >> 1) & 3)) * 8;

    for (int k0 = 0; k0 < K; k0 += 32) {
        __syncthreads();
#pragma unroll
        for (int i = 0; i < 2; ++i) {
            __builtin_amdgcn_global_load_lds(
                (const __attribute__((address_space(1))) uint32_t*)(const void*)(Ag + (size_t)i * 64 * K + k0),
                (__attribute__((address_space(3))) uint32_t*)(void*)(Asw + i * 64 * 32),
                16, 0, 0);
            __builtin_amdgcn_global_load_lds(
                (const __attribute__((address_space(1))) uint32_t*)(const void*)(Bg + (size_t)i * 64 * K + k0),
                (__attribute__((address_space(3))) uint32_t*)(void*)(Bsw + i * 64 * 32),
                16, 0, 0);
        }
        __syncthreads();

        short8 af[4], bfr[4];
#pragma unroll
        for (int i = 0; i < 4; ++i)
            af[i] = *(const short8*)(As + (wm + i * 16 + fr) * 32 + koff);
#pragma unroll
        for (int j = 0; j < 4; ++j)
            bfr[j] = *(const short8*)(Bs + (wn + j * 16 + fr) * 32 + koff);
#pragma unroll
        for (int i = 0; i < 4; ++i)
#pragma unroll
            for (int j = 0; j < 4; ++j)
                acc[i][j] = __builtin_amdgcn_mfma_f32_16x16x32_bf16(af[i], bfr[j], acc[i][j], 0, 0, 0);
    }

    const int r0row = (lane >> 4) * 4;
#pragma unroll
    for (int i = 0; i < 4; ++i) {
#pragma unroll
        for (int r = 0; r < 4; ++r) {
            size_t row = m0 + wm + i * 16 + r0row + r;
#pragma unroll
            for (int j = 0; j < 4; ++j) {
                size_t col = n0 + wn + j * 16 + fr;
                float v = acc[i][j][r];
                if (OUT_BF16)
                    ((u16*)C)[row * N + col] = (u16)f2bf_bits(v);
                else
                    ((float*)C)[row * N + col] = v;
            }
        }
    }
}

// ============================================================
// scan: per element  a = sigmoid(-g), v = sigmoid(g)*(relu(h)+0.5)
// recurrence h_t = a_t * h_{t-1} + v_t
// hg layout: u16[M][4096], hidden at col c (<2048), gate at 2048+c.
// Thread handles EIGHT channels (uint4 16B loads), 2-row rolling prefetch.
// ============================================================
__device__ __forceinline__ void av_pair(uint32_t hh, uint32_t gg,
                                        float& a0, float& v0, float& a1, float& v1) {
    float h0 = bflo(hh), h1 = bfhi(hh);
    float g0 = bflo(gg), g1 = bfhi(gg);
    g0 = fminf(fmaxf(g0, -30.f), 30.f);
    g1 = fminf(fmaxf(g1, -30.f), 30.f);
    float e0 = __expf(-g0), e1 = __expf(-g1);
    float z0 = 1.f / (1.f + e0), z1 = 1.f / (1.f + e1);
    a0 = e0 * z0;
    a1 = e1 * z1;
    v0 = z0 * (fmaxf(h0, 0.f) + 0.5f);
    v1 = z1 * (fmaxf(h1, 0.f) + 0.5f);
}

__device__ __forceinline__ void av8(uint4 hh, uint4 gg, float* a, float* v) {
    av_pair(hh.x, gg.x, a[0], v[0], a[1], v[1]);
    av_pair(hh.y, gg.y, a[2], v[2], a[3], v[3]);
    av_pair(hh.z, gg.z, a[4], v[4], a[5], v[5]);
    av_pair(hh.w, gg.w, a[6], v[6], a[7], v[7]);
}

// Phase A: per-chunk affine summary. grid (NCHUNK, BATCH) x 256 thr.
__global__ __launch_bounds__(256) void scan_chunks(const u16* __restrict__ hg,
                                                   float2* __restrict__ sumAV) {
    const int b = blockIdx.y, ch = blockIdx.x;
    const int c8 = threadIdx.x * 8;
    const size_t rowbase = (size_t)b * SEQ + (size_t)ch * CLEN;
    const u16* p = hg + rowbase * 4096 + c8;
    float A[8], V[8];
#pragma unroll
    for (int k = 0; k < 8; ++k) { A[k] = 1.f; V[k] = 0.f; }
    uint4 h0 = *(const uint4*)(p);
    uint4 g0 = *(const uint4*)(p + 2048);
    uint4 h1 = *(const uint4*)(p + 4096);
    uint4 g1 = *(const uint4*)(p + 4096 + 2048);
#pragma unroll 4
    for (int j = 0; j < CLEN; ++j) {
        uint4 h2, g2;
        if (j + 2 < CLEN) {
            h2 = *(const uint4*)(p + (size_t)(j + 2) * 4096);
            g2 = *(const uint4*)(p + (size_t)(j + 2) * 4096 + 2048);
        }
        float a[8], v[8];
        av8(h0, g0, a, v);
#pragma unroll
        for (int k = 0; k < 8; ++k) { V[k] = fmaf(a[k], V[k], v[k]); A[k] *= a[k]; }
        h0 = h1; g0 = g1; h1 = h2; g1 = g2;
    }
    float4* dst = (float4*)(sumAV + (size_t)(b * NCHUNK + ch) * 2048 + c8);
    dst[0] = (float4){A[0], V[0], A[1], V[1]};
    dst[1] = (float4){A[2], V[2], A[3], V[3]};
    dst[2] = (float4){A[4], V[4], A[5], V[5]};
    dst[3] = (float4){A[6], V[6], A[7], V[7]};
}

// Phase B: sequential carry scan over NCHUNK chunk summaries per chain.
// 128 blocks x 64 threads; thread -> one (b, channel) chain of NCHUNK links.
__global__ __launch_bounds__(64) void scan_carry(const float2* __restrict__ sumAV,
                                                 float* __restrict__ carry) {
    const int g = blockIdx.x * 64 + threadIdx.x;  // 0..8191
    const int b = g >> 11, c = g & 2047;
    float h = 0.f;
#pragma unroll 8
    for (int ch = 0; ch < NCHUNK; ++ch) {
        float2 s = sumAV[(size_t)(b * NCHUNK + ch) * 2048 + c];
        carry[(size_t)(b * NCHUNK + ch) * 2048 + c] = h;
        h = fmaf(s.x, h, s.y);
    }
}

// Phase C: replay chunk with carry-in, emit h as bf16 (uint4 stores).
__global__ __launch_bounds__(256) void scan_apply(const u16* __restrict__ hg,
                                                  const float* __restrict__ carry,
                                                  uint32_t* __restrict__ hbuf) {
    const int b = blockIdx.y, ch = blockIdx.x;
    const int c8 = threadIdx.x * 8;
    const size_t rowbase = (size_t)b * SEQ + (size_t)ch * CLEN;
    const u16* p = hg + rowbase * 4096 + c8;
    uint32_t* q = hbuf + rowbase * 1024 + c8 / 2;
    const float4* cin = (const float4*)(carry + (size_t)(b * NCHUNK + ch) * 2048 + c8);
    float4 cl = cin[0], chh = cin[1];
    float H[8] = {cl.x, cl.y, cl.z, cl.w, chh.x, chh.y, chh.z, chh.w};
    uint4 h0 = *(const uint4*)(p);
    uint4 g0 = *(const uint4*)(p + 2048);
    uint4 h1 = *(const uint4*)(p + 4096);
    uint4 g1 = *(const uint4*)(p + 4096 + 2048);
#pragma unroll 4
    for (int j = 0; j < CLEN; ++j) {
        uint4 h2, g2;
        if (j + 2 < CLEN) {
            h2 = *(const uint4*)(p + (size_t)(j + 2) * 4096);
            g2 = *(const uint4*)(p + (size_t)(j + 2) * 4096 + 2048);
        }
        float a[8], v[8];
        av8(h0, g0, a, v);
#pragma unroll
        for (int k = 0; k < 8; ++k) H[k] = fmaf(a[k], H[k], v[k]);
        uint4 o;
        o.x = f2bf_bits(H[0]) | (f2bf_bits(H[1]) << 16);
        o.y = f2bf_bits(H[2]) | (f2bf_bits(H[3]) << 16);
        o.z = f2bf_bits(H[4]) | (f2bf_bits(H[5]) << 16);
        o.w = f2bf_bits(H[6]) | (f2bf_bits(H[7]) << 16);
        *(uint4*)(q + (size_t)j * 1024) = o;
        h0 = h1; g0 = g1; h1 = h2; g1 = g2;
    }
}

// ============================================================
extern "C" void kernel_launch(void* const* d_in, const int* in_sizes, int n_in,
                              void* d_out, int out_size, void* d_ws, size_t ws_size,
                              hipStream_t stream) {
    const float* x = (const float*)d_in[0];     // [16384,1024]
    const float* Whg = (const float*)d_in[1];   // [1024,4096]
    const float* Wout = (const float*)d_in[2];  // [2048,1024]

    char* ws = (char*)d_ws;
    size_t off = 0;
    u16* xb = (u16*)(ws + off);        off += (size_t)M_TOTAL * DIMX * 2;        // 32 MB
    u16* whgt = (u16*)(ws + off);      off += (size_t)N_HG * DIMX * 2;           // 8 MB
    u16* woutt = (u16*)(ws + off);     off += (size_t)DIMX * DIM_INNER * 2;      // 4 MB
    u16* hg = (u16*)(ws + off);        off += (size_t)M_TOTAL * N_HG * 2;        // 128 MB
    uint32_t* hbuf = (uint32_t*)(ws + off); off += (size_t)M_TOTAL * DIM_INNER * 2; // 64 MB
    // sumAV (16.8 MB) + carry (8.4 MB) alias xb's region (32 MB): xb is dead
    // after GEMM1, which completes before scan_chunks on the same stream.
    float2* sumAV = (float2*)(ws + 0);
    float* carry = (float*)(ws + (size_t)BATCH * NCHUNK * DIM_INNER * 8);

    // 1. fused prep: cast x, transpose Whg, transpose Wout
    prep<<<2048 + 1024 + 512, 256, 0, stream>>>(x, Whg, Wout, xb, whgt, woutt);

    // 2. GEMM1: hg[16384][4096] = xb @ Whg   (bf16 out)
    gemm_bf16<1><<<dim3(N_HG / 128, M_TOTAL / 128), 256, 0, stream>>>(xb, whgt, hg, M_TOTAL, N_HG, DIMX);

    // 3. chunked scan over S  (1024 blocks -> 16 waves/CU)
    scan_chunks<<<dim3(NCHUNK, BATCH), 256, 0, stream>>>(hg, sumAV);
    scan_carry<<<dim3(128), 64, 0, stream>>>(sumAV, carry);
    scan_apply<<<dim3(NCHUNK, BATCH), 256, 0, stream>>>(hg, carry, hbuf);

    // 4. GEMM2: out[16384][1024] = h @ Wout  (fp32 out)
    gemm_bf16<0><<<dim3(DIMX / 128, M_TOTAL / 128), 256, 0, stream>>>((const u16*)hbuf, woutt, d_out, M_TOTAL, DIMX, DIM_INNER);
}

// Round 7
// 457.222 us; speedup vs baseline: 1.0096x; 1.0096x over previous
//
#include <hip/hip_runtime.h>
#include <stdint.h>

// ---- problem constants ----
#define DIMX 1024
#define DIM_INNER 2048
#define BATCH 4
#define SEQ 4096
#define M_TOTAL (BATCH * SEQ)   // 16384
#define N_HG (2 * DIM_INNER)    // 4096
#define NCHUNK 128              // chunks along S (R5 best)
#define CLEN 32                 // steps per chunk

typedef unsigned short u16;
typedef __attribute__((ext_vector_type(8))) short short8;   // 8 x bf16 MFMA frag
typedef __attribute__((ext_vector_type(4))) float floatx4;  // MFMA acc

// ---- bf16 helpers (bit-level, RNE) ----
__device__ __forceinline__ float bflo(uint32_t u) { return __uint_as_float(u << 16); }
__device__ __forceinline__ float bfhi(uint32_t u) { return __uint_as_float(u & 0xffff0000u); }
__device__ __forceinline__ uint32_t f2bf_bits(float f) {
    uint32_t u = __float_as_uint(f);
    return (u + 0x7fffu + ((u >> 16) & 1u)) >> 16;  // round-to-nearest-even
}

// ============================================================
// prep kernel: fuses x-cast + Whg transpose + Wout transpose.
// ============================================================
__global__ __launch_bounds__(256) void prep(const float* __restrict__ x,
                                            const float* __restrict__ Whg,
                                            const float* __restrict__ Wout,
                                            u16* __restrict__ xb,
                                            u16* __restrict__ whgt,
                                            u16* __restrict__ woutt) {
    __shared__ float tile[64][65];
    const int bid = blockIdx.x;
    const int tid = threadIdx.x;
    if (bid < 2048) {
        const int n4 = M_TOTAL * DIMX / 4;
        const float4* in4 = (const float4*)x;
        ushort4* out4 = (ushort4*)xb;
        for (int i = bid * 256 + tid; i < n4; i += 2048 * 256) {
            float4 v = in4[i];
            ushort4 o;
            o.x = (u16)f2bf_bits(v.x);
            o.y = (u16)f2bf_bits(v.y);
            o.z = (u16)f2bf_bits(v.z);
            o.w = (u16)f2bf_bits(v.w);
            out4[i] = o;
        }
        return;
    }
    const float* in;
    u16* out;
    int R, C, tb;
    if (bid < 3072) {
        in = Whg; out = whgt; R = DIMX; C = N_HG; tb = bid - 2048;
    } else {
        in = Wout; out = woutt; R = DIM_INNER; C = DIMX; tb = bid - 3072;
    }
    const int tilesx = C / 64;
    const int c0 = (tb % tilesx) * 64, r0 = (tb / tilesx) * 64;
    const int tx = tid & 63, ty = tid >> 6;  // 64 x 4
#pragma unroll
    for (int i = ty; i < 64; i += 4)
        tile[i][tx] = in[(size_t)(r0 + i) * C + c0 + tx];
    __syncthreads();
#pragma unroll
    for (int i = ty; i < 64; i += 4)
        out[(size_t)(c0 + i) * R + r0 + tx] = (u16)f2bf_bits(tile[tx][i]);
}

// ============================================================
// bf16 MFMA GEMM core: C[M][N] = A[M][K] * Bt[N][K]^T.
// 128x128 block tile, BK=32, 256 threads, global_load_lds width-16 staging,
// XOR k-block swizzle (R3: LDS conflicts -> 0).
//
// R7: 1-D grid + XCD-locality super-tile swizzle. 64-block super-tile covers
// 8 m-tiles x 8 n-tiles; lin%8 selects m within the super-tile. With HW
// round-robin lin->XCD, each XCD sees ONE m-tile per super-tile (A panel
// 512KB, L2-resident, read by 8 n-blocks) and B stays LLC/L2-resident.
// NT8 = (N/128)/8 super-tile columns (compile-time).
// ============================================================
template <int OUT_BF16, int NT8>
__device__ __forceinline__ void gemm_impl(const u16* __restrict__ A,
                                          const u16* __restrict__ Bt,
                                          void* __restrict__ C,
                                          const int M, const int N, const int K) {
    __shared__ alignas(16) u16 As[128 * 32];
    __shared__ alignas(16) u16 Bs[128 * 32];

    const int lin = blockIdx.x;
    const int ml = lin & 7;            // m-tile within super-tile (== XCD slot)
    const int nl = (lin >> 3) & 7;     // n-tile within super-tile
    const int st = lin >> 6;           // super-tile index
    const int stx = st % NT8, sty = st / NT8;
    const size_t m0 = (size_t)(sty * 8 + ml) * 128;
    const size_t n0 = (size_t)(stx * 8 + nl) * 128;

    const int tid = threadIdx.x;
    const int lane = tid & 63;
    const int wave = tid >> 6;
    const int wm = (wave >> 1) * 64;
    const int wn = (wave & 1) * 64;

    floatx4 acc[4][4];
#pragma unroll
    for (int i = 0; i < 4; ++i)
#pragma unroll
        for (int j = 0; j < 4; ++j) acc[i][j] = (floatx4){0.f, 0.f, 0.f, 0.f};

    const int srow = lane >> 2;
    const int scol = ((lane & 3) ^ ((srow >> 1) & 3)) * 8;
    const u16* Ag = A + m0 * K + (size_t)(wave * 16 + srow) * K + scol;
    const u16* Bg = Bt + n0 * K + (size_t)(wave * 16 + srow) * K + scol;
    u16* Asw = As + (wave * 16) * 32;
    u16* Bsw = Bs + (wave * 16) * 32;

    const int fr = lane & 15;
    const int kblk = lane >> 4;
    const int koff = (kblk ^ ((fr >> 1) & 3)) * 8;

    for (int k0 = 0; k0 < K; k0 += 32) {
        __syncthreads();
#pragma unroll
        for (int i = 0; i < 2; ++i) {
            __builtin_amdgcn_global_load_lds(
                (const __attribute__((address_space(1))) uint32_t*)(const void*)(Ag + (size_t)i * 64 * K + k0),
                (__attribute__((address_space(3))) uint32_t*)(void*)(Asw + i * 64 * 32),
                16, 0, 0);
            __builtin_amdgcn_global_load_lds(
                (const __attribute__((address_space(1))) uint32_t*)(const void*)(Bg + (size_t)i * 64 * K + k0),
                (__attribute__((address_space(3))) uint32_t*)(void*)(Bsw + i * 64 * 32),
                16, 0, 0);
        }
        __syncthreads();

        short8 af[4], bfr[4];
#pragma unroll
        for (int i = 0; i < 4; ++i)
            af[i] = *(const short8*)(As + (wm + i * 16 + fr) * 32 + koff);
#pragma unroll
        for (int j = 0; j < 4; ++j)
            bfr[j] = *(const short8*)(Bs + (wn + j * 16 + fr) * 32 + koff);
#pragma unroll
        for (int i = 0; i < 4; ++i)
#pragma unroll
            for (int j = 0; j < 4; ++j)
                acc[i][j] = __builtin_amdgcn_mfma_f32_16x16x32_bf16(af[i], bfr[j], acc[i][j], 0, 0, 0);
    }

    const int r0row = (lane >> 4) * 4;
#pragma unroll
    for (int i = 0; i < 4; ++i) {
#pragma unroll
        for (int r = 0; r < 4; ++r) {
            size_t row = m0 + wm + i * 16 + r0row + r;
#pragma unroll
            for (int j = 0; j < 4; ++j) {
                size_t col = n0 + wn + j * 16 + fr;
                float v = acc[i][j][r];
                if (OUT_BF16)
                    ((u16*)C)[row * N + col] = (u16)f2bf_bits(v);
                else
                    ((float*)C)[row * N + col] = v;
            }
        }
    }
}

// distinct symbols for profiler attribution
__global__ __launch_bounds__(256, 2) void gemm1_k(const u16* __restrict__ A,
                                                  const u16* __restrict__ Bt,
                                                  u16* __restrict__ C) {
    gemm_impl<1, 4>(A, Bt, C, M_TOTAL, N_HG, DIMX);       // NT = 32 tiles -> NT8 = 4
}
__global__ __launch_bounds__(256, 2) void gemm2_k(const u16* __restrict__ A,
                                                  const u16* __restrict__ Bt,
                                                  float* __restrict__ C) {
    gemm_impl<0, 1>(A, Bt, C, M_TOTAL, DIMX, DIM_INNER);  // NT = 8 tiles -> NT8 = 1
}

// ============================================================
// scan: a = sigmoid(-g), v = sigmoid(g)*(relu(h)+0.5); h_t = a_t h_{t-1} + v_t
// hg layout: u16[M][4096], hidden at col c (<2048), gate at 2048+c.
// Thread handles EIGHT channels (uint4 16B loads), 2-row rolling prefetch.
// ============================================================
__device__ __forceinline__ void av_pair(uint32_t hh, uint32_t gg,
                                        float& a0, float& v0, float& a1, float& v1) {
    float h0 = bflo(hh), h1 = bfhi(hh);
    float g0 = bflo(gg), g1 = bfhi(gg);
    g0 = fminf(fmaxf(g0, -30.f), 30.f);
    g1 = fminf(fmaxf(g1, -30.f), 30.f);
    float e0 = __expf(-g0), e1 = __expf(-g1);
    float z0 = 1.f / (1.f + e0), z1 = 1.f / (1.f + e1);
    a0 = e0 * z0;
    a1 = e1 * z1;
    v0 = z0 * (fmaxf(h0, 0.f) + 0.5f);
    v1 = z1 * (fmaxf(h1, 0.f) + 0.5f);
}

__device__ __forceinline__ void av8(uint4 hh, uint4 gg, float* a, float* v) {
    av_pair(hh.x, gg.x, a[0], v[0], a[1], v[1]);
    av_pair(hh.y, gg.y, a[2], v[2], a[3], v[3]);
    av_pair(hh.z, gg.z, a[4], v[4], a[5], v[5]);
    av_pair(hh.w, gg.w, a[6], v[6], a[7], v[7]);
}

// Phase A: per-chunk affine summary. grid (NCHUNK, BATCH) x 256 thr.
__global__ __launch_bounds__(256) void scan_chunks(const u16* __restrict__ hg,
                                                   float2* __restrict__ sumAV) {
    const int b = blockIdx.y, ch = blockIdx.x;
    const int c8 = threadIdx.x * 8;
    const size_t rowbase = (size_t)b * SEQ + (size_t)ch * CLEN;
    const u16* p = hg + rowbase * 4096 + c8;
    float A[8], V[8];
#pragma unroll
    for (int k = 0; k < 8; ++k) { A[k] = 1.f; V[k] = 0.f; }
    uint4 h0 = *(const uint4*)(p);
    uint4 g0 = *(const uint4*)(p + 2048);
    uint4 h1 = *(const uint4*)(p + 4096);
    uint4 g1 = *(const uint4*)(p + 4096 + 2048);
#pragma unroll 4
    for (int j = 0; j < CLEN; ++j) {
        uint4 h2, g2;
        if (j + 2 < CLEN) {
            h2 = *(const uint4*)(p + (size_t)(j + 2) * 4096);
            g2 = *(const uint4*)(p + (size_t)(j + 2) * 4096 + 2048);
        }
        float a[8], v[8];
        av8(h0, g0, a, v);
#pragma unroll
        for (int k = 0; k < 8; ++k) { V[k] = fmaf(a[k], V[k], v[k]); A[k] *= a[k]; }
        h0 = h1; g0 = g1; h1 = h2; g1 = g2;
    }
    float4* dst = (float4*)(sumAV + (size_t)(b * NCHUNK + ch) * 2048 + c8);
    dst[0] = (float4){A[0], V[0], A[1], V[1]};
    dst[1] = (float4){A[2], V[2], A[3], V[3]};
    dst[2] = (float4){A[4], V[4], A[5], V[5]};
    dst[3] = (float4){A[6], V[6], A[7], V[7]};
}

// Phase B: sequential carry scan. 128 blocks x 64 threads.
__global__ __launch_bounds__(64) void scan_carry(const float2* __restrict__ sumAV,
                                                 float* __restrict__ carry) {
    const int g = blockIdx.x * 64 + threadIdx.x;  // 0..8191
    const int b = g >> 11, c = g & 2047;
    float h = 0.f;
#pragma unroll 8
    for (int ch = 0; ch < NCHUNK; ++ch) {
        float2 s = sumAV[(size_t)(b * NCHUNK + ch) * 2048 + c];
        carry[(size_t)(b * NCHUNK + ch) * 2048 + c] = h;
        h = fmaf(s.x, h, s.y);
    }
}

// Phase C: replay chunk with carry-in, emit h as bf16 (uint4 stores).
__global__ __launch_bounds__(256) void scan_apply(const u16* __restrict__ hg,
                                                  const float* __restrict__ carry,
                                                  uint32_t* __restrict__ hbuf) {
    const int b = blockIdx.y, ch = blockIdx.x;
    const int c8 = threadIdx.x * 8;
    const size_t rowbase = (size_t)b * SEQ + (size_t)ch * CLEN;
    const u16* p = hg + rowbase * 4096 + c8;
    uint32_t* q = hbuf + rowbase * 1024 + c8 / 2;
    const float4* cin = (const float4*)(carry + (size_t)(b * NCHUNK + ch) * 2048 + c8);
    float4 cl = cin[0], chh = cin[1];
    float H[8] = {cl.x, cl.y, cl.z, cl.w, chh.x, chh.y, chh.z, chh.w};
    uint4 h0 = *(const uint4*)(p);
    uint4 g0 = *(const uint4*)(p + 2048);
    uint4 h1 = *(const uint4*)(p + 4096);
    uint4 g1 = *(const uint4*)(p + 4096 + 2048);
#pragma unroll 4
    for (int j = 0; j < CLEN; ++j) {
        uint4 h2, g2;
        if (j + 2 < CLEN) {
            h2 = *(const uint4*)(p + (size_t)(j + 2) * 4096);
            g2 = *(const uint4*)(p + (size_t)(j + 2) * 4096 + 2048);
        }
        float a[8], v[8];
        av8(h0, g0, a, v);
#pragma unroll
        for (int k = 0; k < 8; ++k) H[k] = fmaf(a[k], H[k], v[k]);
        uint4 o;
        o.x = f2bf_bits(H[0]) | (f2bf_bits(H[1]) << 16);
        o.y = f2bf_bits(H[2]) | (f2bf_bits(H[3]) << 16);
        o.z = f2bf_bits(H[4]) | (f2bf_bits(H[5]) << 16);
        o.w = f2bf_bits(H[6]) | (f2bf_bits(H[7]) << 16);
        *(uint4*)(q + (size_t)j * 1024) = o;
        h0 = h1; g0 = g1; h1 = h2; g1 = g2;
    }
}

// ============================================================
extern "C" void kernel_launch(void* const* d_in, const int* in_sizes, int n_in,
                              void* d_out, int out_size, void* d_ws, size_t ws_size,
                              hipStream_t stream) {
    const float* x = (const float*)d_in[0];     // [16384,1024]
    const float* Whg = (const float*)d_in[1];   // [1024,4096]
    const float* Wout = (const float*)d_in[2];  // [2048,1024]

    char* ws = (char*)d_ws;
    size_t off = 0;
    u16* xb = (u16*)(ws + off);        off += (size_t)M_TOTAL * DIMX * 2;        // 32 MB
    u16* whgt = (u16*)(ws + off);      off += (size_t)N_HG * DIMX * 2;           // 8 MB
    u16* woutt = (u16*)(ws + off);     off += (size_t)DIMX * DIM_INNER * 2;      // 4 MB
    u16* hg = (u16*)(ws + off);        off += (size_t)M_TOTAL * N_HG * 2;        // 128 MB
    uint32_t* hbuf = (uint32_t*)(ws + off); off += (size_t)M_TOTAL * DIM_INNER * 2; // 64 MB
    // sumAV (8.4 MB) + carry (4.2 MB) alias xb (dead after gemm1).
    float2* sumAV = (float2*)(ws + 0);
    float* carry = (float*)(ws + (size_t)BATCH * NCHUNK * DIM_INNER * 8);

    // 1. fused prep
    prep<<<2048 + 1024 + 512, 256, 0, stream>>>(x, Whg, Wout, xb, whgt, woutt);

    // 2. GEMM1: hg = xb @ Whg (bf16 out), 4096 blocks, swizzled 1-D grid
    gemm1_k<<<4096, 256, 0, stream>>>(xb, whgt, hg);

    // 3. chunked scan over S
    scan_chunks<<<dim3(NCHUNK, BATCH), 256, 0, stream>>>(hg, sumAV);
    scan_carry<<<dim3(128), 64, 0, stream>>>(sumAV, carry);
    scan_apply<<<dim3(NCHUNK, BATCH), 256, 0, stream>>>(hg, carry, hbuf);

    // 4. GEMM2: out = h @ Wout (fp32 out), 1024 blocks, swizzled 1-D grid
    gemm2_k<<<1024, 256, 0, stream>>>((const u16*)hbuf, woutt, (float*)d_out);
}

// Round 8
// 421.918 us; speedup vs baseline: 1.0940x; 1.0837x over previous
//
#include <hip/hip_runtime.h>
#include <stdint.h>

// ---- problem constants ----
#define DIMX 1024
#define DIM_INNER 2048
#define BATCH 4
#define SEQ 4096
#define M_TOTAL (BATCH * SEQ)   // 16384
#define N_HG (2 * DIM_INNER)    // 4096
#define NCHUNK 32               // chunks along S (= GEMM1 m-tiles per batch)
#define CLEN 128                // steps per chunk (= GEMM1 m-tile rows)

typedef unsigned short u16;
typedef __attribute__((ext_vector_type(8))) short short8;   // 8 x bf16 MFMA frag
typedef __attribute__((ext_vector_type(4))) float floatx4;  // MFMA acc

// ---- bf16 helpers (bit-level, RNE) ----
__device__ __forceinline__ float bflo(uint32_t u) { return __uint_as_float(u << 16); }
__device__ __forceinline__ float bfhi(uint32_t u) { return __uint_as_float(u & 0xffff0000u); }
__device__ __forceinline__ uint32_t f2bf_bits(float f) {
    uint32_t u = __float_as_uint(f);
    return (u + 0x7fffu + ((u >> 16) & 1u)) >> 16;  // round-to-nearest-even
}

// ============================================================
// prep kernel: fuses x-cast + Whg transpose + Wout transpose.
// ============================================================
__global__ __launch_bounds__(256) void prep(const float* __restrict__ x,
                                            const float* __restrict__ Whg,
                                            const float* __restrict__ Wout,
                                            u16* __restrict__ xb,
                                            u16* __restrict__ whgt,
                                            u16* __restrict__ woutt) {
    __shared__ float tile[64][65];
    const int bid = blockIdx.x;
    const int tid = threadIdx.x;
    if (bid < 2048) {
        const int n4 = M_TOTAL * DIMX / 4;
        const float4* in4 = (const float4*)x;
        ushort4* out4 = (ushort4*)xb;
        for (int i = bid * 256 + tid; i < n4; i += 2048 * 256) {
            float4 v = in4[i];
            ushort4 o;
            o.x = (u16)f2bf_bits(v.x);
            o.y = (u16)f2bf_bits(v.y);
            o.z = (u16)f2bf_bits(v.z);
            o.w = (u16)f2bf_bits(v.w);
            out4[i] = o;
        }
        return;
    }
    const float* in;
    u16* out;
    int R, C, tb;
    if (bid < 3072) {
        in = Whg; out = whgt; R = DIMX; C = N_HG; tb = bid - 2048;
    } else {
        in = Wout; out = woutt; R = DIM_INNER; C = DIMX; tb = bid - 3072;
    }
    const int tilesx = C / 64;
    const int c0 = (tb % tilesx) * 64, r0 = (tb / tilesx) * 64;
    const int tx = tid & 63, ty = tid >> 6;  // 64 x 4
#pragma unroll
    for (int i = ty; i < 64; i += 4)
        tile[i][tx] = in[(size_t)(r0 + i) * C + c0 + tx];
    __syncthreads();
#pragma unroll
    for (int i = ty; i < 64; i += 4)
        out[(size_t)(c0 + i) * R + r0 + tx] = (u16)f2bf_bits(tile[tx][i]);
}

// ============================================================
// GEMM1 fused: per block computes hidden tile (cols n0..n0+127 of first
// 2048) AND gate tile (same channels, rows 2048+n0.. of whgt) with two B
// panels and 32 MFMA per K-iter.  Epilogue computes (a,v) lane-locally in
// fp32, writes packed bf16 (a,v) to global, and computes the per-chunk
// affine summary (A = prod a, V = scan value) in-block via an LDS
// transpose (smem unioned with the staging buffers).
// grid (16, 128): x = channel-tile (2048/128), y = m-tile (= global chunk).
// ============================================================
__global__ __launch_bounds__(256, 2) void gemm1_k(const u16* __restrict__ A,
                                                  const u16* __restrict__ Bt,
                                                  uint32_t* __restrict__ av,
                                                  float2* __restrict__ sumAV) {
    __shared__ alignas(16) char smem[65536];
    u16* As = (u16*)smem;             // 128x32 u16 = 8 KB
    u16* Bh = (u16*)(smem + 8192);    // 8 KB
    u16* Bg = (u16*)(smem + 16384);   // 8 KB
    uint32_t* avl = (uint32_t*)smem;  // [128][128] packed (a,v), reused after K-loop

    const int tid = threadIdx.x;
    const int lane = tid & 63;
    const int wave = tid >> 6;
    const int wm = (wave >> 1) * 64;
    const int wn = (wave & 1) * 64;
    const size_t m0 = (size_t)blockIdx.y * 128;
    const int n0 = blockIdx.x * 128;   // channel-tile base (0..2047)

    floatx4 acch[4][4], accg[4][4];
#pragma unroll
    for (int i = 0; i < 4; ++i)
#pragma unroll
        for (int j = 0; j < 4; ++j) {
            acch[i][j] = (floatx4){0.f, 0.f, 0.f, 0.f};
            accg[i][j] = (floatx4){0.f, 0.f, 0.f, 0.f};
        }

    const int srow = lane >> 2;
    const int scol = ((lane & 3) ^ ((srow >> 1) & 3)) * 8;  // XOR k-swizzle
    const u16* Ag = A + m0 * DIMX + (size_t)(wave * 16 + srow) * DIMX + scol;
    const u16* Bhg = Bt + (size_t)n0 * DIMX + (size_t)(wave * 16 + srow) * DIMX + scol;
    const u16* Bgg = Bt + (size_t)(DIM_INNER + n0) * DIMX + (size_t)(wave * 16 + srow) * DIMX + scol;
    u16* Asw = As + (wave * 16) * 32;
    u16* Bhw = Bh + (wave * 16) * 32;
    u16* Bgw = Bg + (wave * 16) * 32;

    const int fr = lane & 15;
    const int kblk = lane >> 4;
    const int koff = (kblk ^ ((fr >> 1) & 3)) * 8;

    for (int k0 = 0; k0 < DIMX; k0 += 32) {
        __syncthreads();
#pragma unroll
        for (int i = 0; i < 2; ++i) {
            __builtin_amdgcn_global_load_lds(
                (const __attribute__((address_space(1))) uint32_t*)(const void*)(Ag + (size_t)i * 64 * DIMX + k0),
                (__attribute__((address_space(3))) uint32_t*)(void*)(Asw + i * 64 * 32), 16, 0, 0);
            __builtin_amdgcn_global_load_lds(
                (const __attribute__((address_space(1))) uint32_t*)(const void*)(Bhg + (size_t)i * 64 * DIMX + k0),
                (__attribute__((address_space(3))) uint32_t*)(void*)(Bhw + i * 64 * 32), 16, 0, 0);
            __builtin_amdgcn_global_load_lds(
                (const __attribute__((address_space(1))) uint32_t*)(const void*)(Bgg + (size_t)i * 64 * DIMX + k0),
                (__attribute__((address_space(3))) uint32_t*)(void*)(Bgw + i * 64 * 32), 16, 0, 0);
        }
        __syncthreads();

        short8 af[4], bhf[4], bgf[4];
#pragma unroll
        for (int i = 0; i < 4; ++i)
            af[i] = *(const short8*)(As + (wm + i * 16 + fr) * 32 + koff);
#pragma unroll
        for (int j = 0; j < 4; ++j) {
            bhf[j] = *(const short8*)(Bh + (wn + j * 16 + fr) * 32 + koff);
            bgf[j] = *(const short8*)(Bg + (wn + j * 16 + fr) * 32 + koff);
        }
#pragma unroll
        for (int i = 0; i < 4; ++i)
#pragma unroll
            for (int j = 0; j < 4; ++j) {
                acch[i][j] = __builtin_amdgcn_mfma_f32_16x16x32_bf16(af[i], bhf[j], acch[i][j], 0, 0, 0);
                accg[i][j] = __builtin_amdgcn_mfma_f32_16x16x32_bf16(af[i], bgf[j], accg[i][j], 0, 0, 0);
            }
    }
    __syncthreads();  // staging LDS dead; safe to reuse as avl

    // epilogue: (a,v) from fp32 accs; write global av + LDS transpose copy
    const int r0row = (lane >> 4) * 4;
#pragma unroll
    for (int i = 0; i < 4; ++i) {
#pragma unroll
        for (int r = 0; r < 4; ++r) {
            const int row = wm + i * 16 + r0row + r;
#pragma unroll
            for (int j = 0; j < 4; ++j) {
                const int col = wn + j * 16 + fr;
                float h = acch[i][j][r];
                float g = accg[i][j][r];
                g = fminf(fmaxf(g, -30.f), 30.f);
                float e = __expf(-g);
                float z = 1.f / (1.f + e);
                float a = e * z;                      // 1 - sigmoid(g)
                float v = z * (fmaxf(h, 0.f) + 0.5f); // sigmoid(g)*(relu(h)+0.5)
                uint32_t pk = f2bf_bits(a) | (f2bf_bits(v) << 16);
                avl[row * 128 + col] = pk;
                av[(m0 + row) * 2048 + n0 + col] = pk;
            }
        }
    }
    __syncthreads();

    // in-block chunk-summary scan: tid<128 scans rows 0-63 of col tid,
    // tid>=128 scans rows 64-127; compose lo->hi; write sumAV.
    const int col = tid & 127;
    const int rlo = (tid >> 7) * 64;
    float Aa = 1.f, Vv = 0.f;
#pragma unroll 8
    for (int j = 0; j < 64; ++j) {
        uint32_t pk = avl[(rlo + j) * 128 + col];
        float a = bflo(pk), v = bfhi(pk);
        Vv = fmaf(a, Vv, v);
        Aa *= a;
    }
    __syncthreads();
    if (tid < 128) {
        avl[col] = __float_as_uint(Aa);
        avl[128 + col] = __float_as_uint(Vv);
    }
    __syncthreads();
    if (tid >= 128) {
        float Al = __uint_as_float(avl[col]);
        float Vl = __uint_as_float(avl[128 + col]);
        float At = Al * Aa;
        float Vt = fmaf(Aa, Vl, Vv);
        const int chunk = (int)(m0 >> 7);  // global chunk id = b*32+ch
        sumAV[(size_t)chunk * 2048 + n0 + col] = (float2){At, Vt};
    }
}

// ============================================================
// GEMM2: R5's proven 2-D-grid kernel (fp32 out).  grid (8, 128).
// ============================================================
__global__ __launch_bounds__(256, 2) void gemm2_k(const u16* __restrict__ A,
                                                  const u16* __restrict__ Bt,
                                                  float* __restrict__ C) {
    const int M = M_TOTAL, N = DIMX, K = DIM_INNER;
    __shared__ alignas(16) u16 As[128 * 32];
    __shared__ alignas(16) u16 Bs[128 * 32];

    const int tid = threadIdx.x;
    const int lane = tid & 63;
    const int wave = tid >> 6;
    const int wm = (wave >> 1) * 64;
    const int wn = (wave & 1) * 64;
    const size_t m0 = (size_t)blockIdx.y * 128;
    const size_t n0 = (size_t)blockIdx.x * 128;

    floatx4 acc[4][4];
#pragma unroll
    for (int i = 0; i < 4; ++i)
#pragma unroll
        for (int j = 0; j < 4; ++j) acc[i][j] = (floatx4){0.f, 0.f, 0.f, 0.f};

    const int srow = lane >> 2;
    const int scol = ((lane & 3) ^ ((srow >> 1) & 3)) * 8;
    const u16* Ag = A + m0 * K + (size_t)(wave * 16 + srow) * K + scol;
    const u16* Bg = Bt + n0 * K + (size_t)(wave * 16 + srow) * K + scol;
    u16* Asw = As + (wave * 16) * 32;
    u16* Bsw = Bs + (wave * 16) * 32;

    const int fr = lane & 15;
    const int kblk = lane >> 4;
    const int koff = (kblk ^ ((fr >> 1) & 3)) * 8;

    for (int k0 = 0; k0 < K; k0 += 32) {
        __syncthreads();
#pragma unroll
        for (int i = 0; i < 2; ++i) {
            __builtin_amdgcn_global_load_lds(
                (const __attribute__((address_space(1))) uint32_t*)(const void*)(Ag + (size_t)i * 64 * K + k0),
                (__attribute__((address_space(3))) uint32_t*)(void*)(Asw + i * 64 * 32), 16, 0, 0);
            __builtin_amdgcn_global_load_lds(
                (const __attribute__((address_space(1))) uint32_t*)(const void*)(Bg + (size_t)i * 64 * K + k0),
                (__attribute__((address_space(3))) uint32_t*)(void*)(Bsw + i * 64 * 32), 16, 0, 0);
        }
        __syncthreads();

        short8 af[4], bfr[4];
#pragma unroll
        for (int i = 0; i < 4; ++i)
            af[i] = *(const short8*)(As + (wm + i * 16 + fr) * 32 + koff);
#pragma unroll
        for (int j = 0; j < 4; ++j)
            bfr[j] = *(const short8*)(Bs + (wn + j * 16 + fr) * 32 + koff);
#pragma unroll
        for (int i = 0; i < 4; ++i)
#pragma unroll
            for (int j = 0; j < 4; ++j)
                acc[i][j] = __builtin_amdgcn_mfma_f32_16x16x32_bf16(af[i], bfr[j], acc[i][j], 0, 0, 0);
    }

    const int r0row = (lane >> 4) * 4;
#pragma unroll
    for (int i = 0; i < 4; ++i)
#pragma unroll
        for (int r = 0; r < 4; ++r) {
            size_t row = m0 + wm + i * 16 + r0row + r;
#pragma unroll
            for (int j = 0; j < 4; ++j) {
                size_t col = n0 + wn + j * 16 + fr;
                C[row * N + col] = acc[i][j][r];
            }
        }
}

// ============================================================
// Phase B: carry scan over 32 chunk summaries per (batch, channel) chain.
// 128 blocks x 64 threads.
// ============================================================
__global__ __launch_bounds__(64) void scan_carry(const float2* __restrict__ sumAV,
                                                 float* __restrict__ carry) {
    const int g = blockIdx.x * 64 + threadIdx.x;  // 0..8191
    const int b = g >> 11, c = g & 2047;
    float h = 0.f;
#pragma unroll 8
    for (int ch = 0; ch < NCHUNK; ++ch) {
        float2 s = sumAV[(size_t)(b * NCHUNK + ch) * 2048 + c];
        carry[(size_t)(b * NCHUNK + ch) * 2048 + c] = h;
        h = fmaf(s.x, h, s.y);
    }
}

// ============================================================
// Phase C: replay chunk from packed (a,v), carry-in, emit h bf16.
// grid (4, NCHUNK, BATCH) x 256 thr; thread -> 2 channels (uint2 loads).
// ============================================================
__global__ __launch_bounds__(256) void scan_apply(const uint32_t* __restrict__ av,
                                                  const float* __restrict__ carry,
                                                  uint32_t* __restrict__ hbuf) {
    const int b = blockIdx.z, ch = blockIdx.y;
    const int c2 = blockIdx.x * 256 + threadIdx.x;  // channel-pair 0..1023
    const size_t rowbase = (size_t)b * SEQ + (size_t)ch * CLEN;
    const uint32_t* p = av + rowbase * 2048 + c2 * 2;
    uint32_t* q = hbuf + rowbase * 1024 + c2;
    const float2 cin = ((const float2*)carry)[(size_t)(b * NCHUNK + ch) * 1024 + c2];
    float h0 = cin.x, h1 = cin.y;
    uint2 p0 = *(const uint2*)(p);
    uint2 p1 = *(const uint2*)(p + 2048);
#pragma unroll 4
    for (int j = 0; j < CLEN; ++j) {
        uint2 p2;
        if (j + 2 < CLEN) p2 = *(const uint2*)(p + (size_t)(j + 2) * 2048);
        float a0 = bflo(p0.x), v0 = bfhi(p0.x);
        float a1 = bflo(p0.y), v1 = bfhi(p0.y);
        h0 = fmaf(a0, h0, v0);
        h1 = fmaf(a1, h1, v1);
        q[(size_t)j * 1024] = f2bf_bits(h0) | (f2bf_bits(h1) << 16);
        p0 = p1;
        p1 = p2;
    }
}

// ============================================================
extern "C" void kernel_launch(void* const* d_in, const int* in_sizes, int n_in,
                              void* d_out, int out_size, void* d_ws, size_t ws_size,
                              hipStream_t stream) {
    const float* x = (const float*)d_in[0];     // [16384,1024]
    const float* Whg = (const float*)d_in[1];   // [1024,4096]
    const float* Wout = (const float*)d_in[2];  // [2048,1024]

    char* ws = (char*)d_ws;
    size_t off = 0;
    u16* xb = (u16*)(ws + off);        off += (size_t)M_TOTAL * DIMX * 2;          // 33.6 MB
    u16* whgt = (u16*)(ws + off);      off += (size_t)N_HG * DIMX * 2;             // 8.4 MB
    u16* woutt = (u16*)(ws + off);     off += (size_t)DIMX * DIM_INNER * 2;        // 4.2 MB
    uint32_t* av = (uint32_t*)(ws + off); off += (size_t)M_TOTAL * DIM_INNER * 4;  // 134.2 MB
    uint32_t* hbuf = (uint32_t*)(ws + off); off += (size_t)M_TOTAL * DIM_INNER * 2; // 67.1 MB
    float2* sumAV = (float2*)(ws + off); off += (size_t)BATCH * NCHUNK * DIM_INNER * 8; // 2.1 MB
    // carry (1 MB) aliases whgt: whgt is dead after gemm1_k, which completes
    // before scan_carry on the same stream.
    float* carry = (float*)whgt;

    // 1. fused prep
    prep<<<2048 + 1024 + 512, 256, 0, stream>>>(x, Whg, Wout, xb, whgt, woutt);

    // 2. GEMM1 fused: av + per-chunk summaries
    gemm1_k<<<dim3(16, 128), 256, 0, stream>>>(xb, whgt, av, sumAV);

    // 3. carry scan (chains of 32) + replay
    scan_carry<<<128, 64, 0, stream>>>(sumAV, carry);
    scan_apply<<<dim3(4, NCHUNK, BATCH), 256, 0, stream>>>(av, carry, hbuf);

    // 4. GEMM2: out = h @ Wout (fp32 out)
    gemm2_k<<<dim3(8, 128), 256, 0, stream>>>((const u16*)hbuf, woutt, (float*)d_out);
}

// Round 9
// 417.220 us; speedup vs baseline: 1.1064x; 1.0113x over previous
//
#include <hip/hip_runtime.h>
#include <stdint.h>

// ---- problem constants ----
#define DIMX 1024
#define DIM_INNER 2048
#define BATCH 4
#define SEQ 4096
#define M_TOTAL (BATCH * SEQ)   // 16384
#define N_HG (2 * DIM_INNER)    // 4096
#define NCHUNK 32               // chunks along S (= GEMM1 m-tiles per batch)
#define CLEN 128                // steps per chunk (= GEMM1 m-tile rows)

typedef unsigned short u16;
typedef __attribute__((ext_vector_type(8))) short short8;   // 8 x bf16 MFMA frag
typedef __attribute__((ext_vector_type(4))) float floatx4;  // MFMA acc

// ---- bf16 helpers (bit-level, RNE) ----
__device__ __forceinline__ float bflo(uint32_t u) { return __uint_as_float(u << 16); }
__device__ __forceinline__ float bfhi(uint32_t u) { return __uint_as_float(u & 0xffff0000u); }
__device__ __forceinline__ uint32_t f2bf_bits(float f) {
    uint32_t u = __float_as_uint(f);
    return (u + 0x7fffu + ((u >> 16) & 1u)) >> 16;  // round-to-nearest-even
}

// ============================================================
// prep kernel: fuses x-cast + Whg transpose + Wout transpose.
// ============================================================
__global__ __launch_bounds__(256) void prep(const float* __restrict__ x,
                                            const float* __restrict__ Whg,
                                            const float* __restrict__ Wout,
                                            u16* __restrict__ xb,
                                            u16* __restrict__ whgt,
                                            u16* __restrict__ woutt) {
    __shared__ float tile[64][65];
    const int bid = blockIdx.x;
    const int tid = threadIdx.x;
    if (bid < 2048) {
        const int n4 = M_TOTAL * DIMX / 4;
        const float4* in4 = (const float4*)x;
        ushort4* out4 = (ushort4*)xb;
        for (int i = bid * 256 + tid; i < n4; i += 2048 * 256) {
            float4 v = in4[i];
            ushort4 o;
            o.x = (u16)f2bf_bits(v.x);
            o.y = (u16)f2bf_bits(v.y);
            o.z = (u16)f2bf_bits(v.z);
            o.w = (u16)f2bf_bits(v.w);
            out4[i] = o;
        }
        return;
    }
    const float* in;
    u16* out;
    int R, C, tb;
    if (bid < 3072) {
        in = Whg; out = whgt; R = DIMX; C = N_HG; tb = bid - 2048;
    } else {
        in = Wout; out = woutt; R = DIM_INNER; C = DIMX; tb = bid - 3072;
    }
    const int tilesx = C / 64;
    const int c0 = (tb % tilesx) * 64, r0 = (tb / tilesx) * 64;
    const int tx = tid & 63, ty = tid >> 6;  // 64 x 4
#pragma unroll
    for (int i = ty; i < 64; i += 4)
        tile[i][tx] = in[(size_t)(r0 + i) * C + c0 + tx];
    __syncthreads();
#pragma unroll
    for (int i = ty; i < 64; i += 4)
        out[(size_t)(c0 + i) * R + r0 + tx] = (u16)f2bf_bits(tile[tx][i]);
}

// ============================================================
// GEMM1 fused (R8, unchanged): hidden+gate tiles, 32 MFMA/iter; epilogue
// computes (a,v), writes packed bf16 av + in-block chunk summary (A,V).
// grid (16, 128).
// ============================================================
__global__ __launch_bounds__(256, 2) void gemm1_k(const u16* __restrict__ A,
                                                  const u16* __restrict__ Bt,
                                                  uint32_t* __restrict__ av,
                                                  float2* __restrict__ sumAV) {
    __shared__ alignas(16) char smem[65536];
    u16* As = (u16*)smem;             // 128x32 u16 = 8 KB
    u16* Bh = (u16*)(smem + 8192);    // 8 KB
    u16* Bg = (u16*)(smem + 16384);   // 8 KB
    uint32_t* avl = (uint32_t*)smem;  // [128][128] packed (a,v), reused after K-loop

    const int tid = threadIdx.x;
    const int lane = tid & 63;
    const int wave = tid >> 6;
    const int wm = (wave >> 1) * 64;
    const int wn = (wave & 1) * 64;
    const size_t m0 = (size_t)blockIdx.y * 128;
    const int n0 = blockIdx.x * 128;   // channel-tile base (0..2047)

    floatx4 acch[4][4], accg[4][4];
#pragma unroll
    for (int i = 0; i < 4; ++i)
#pragma unroll
        for (int j = 0; j < 4; ++j) {
            acch[i][j] = (floatx4){0.f, 0.f, 0.f, 0.f};
            accg[i][j] = (floatx4){0.f, 0.f, 0.f, 0.f};
        }

    const int srow = lane >> 2;
    const int scol = ((lane & 3) ^ ((srow >> 1) & 3)) * 8;  // XOR k-swizzle
    const u16* Ag = A + m0 * DIMX + (size_t)(wave * 16 + srow) * DIMX + scol;
    const u16* Bhg = Bt + (size_t)n0 * DIMX + (size_t)(wave * 16 + srow) * DIMX + scol;
    const u16* Bgg = Bt + (size_t)(DIM_INNER + n0) * DIMX + (size_t)(wave * 16 + srow) * DIMX + scol;
    u16* Asw = As + (wave * 16) * 32;
    u16* Bhw = Bh + (wave * 16) * 32;
    u16* Bgw = Bg + (wave * 16) * 32;

    const int fr = lane & 15;
    const int kblk = lane >> 4;
    const int koff = (kblk ^ ((fr >> 1) & 3)) * 8;

    for (int k0 = 0; k0 < DIMX; k0 += 32) {
        __syncthreads();
#pragma unroll
        for (int i = 0; i < 2; ++i) {
            __builtin_amdgcn_global_load_lds(
                (const __attribute__((address_space(1))) uint32_t*)(const void*)(Ag + (size_t)i * 64 * DIMX + k0),
                (__attribute__((address_space(3))) uint32_t*)(void*)(Asw + i * 64 * 32), 16, 0, 0);
            __builtin_amdgcn_global_load_lds(
                (const __attribute__((address_space(1))) uint32_t*)(const void*)(Bhg + (size_t)i * 64 * DIMX + k0),
                (__attribute__((address_space(3))) uint32_t*)(void*)(Bhw + i * 64 * 32), 16, 0, 0);
            __builtin_amdgcn_global_load_lds(
                (const __attribute__((address_space(1))) uint32_t*)(const void*)(Bgg + (size_t)i * 64 * DIMX + k0),
                (__attribute__((address_space(3))) uint32_t*)(void*)(Bgw + i * 64 * 32), 16, 0, 0);
        }
        __syncthreads();

        short8 af[4], bhf[4], bgf[4];
#pragma unroll
        for (int i = 0; i < 4; ++i)
            af[i] = *(const short8*)(As + (wm + i * 16 + fr) * 32 + koff);
#pragma unroll
        for (int j = 0; j < 4; ++j) {
            bhf[j] = *(const short8*)(Bh + (wn + j * 16 + fr) * 32 + koff);
            bgf[j] = *(const short8*)(Bg + (wn + j * 16 + fr) * 32 + koff);
        }
#pragma unroll
        for (int i = 0; i < 4; ++i)
#pragma unroll
            for (int j = 0; j < 4; ++j) {
                acch[i][j] = __builtin_amdgcn_mfma_f32_16x16x32_bf16(af[i], bhf[j], acch[i][j], 0, 0, 0);
                accg[i][j] = __builtin_amdgcn_mfma_f32_16x16x32_bf16(af[i], bgf[j], accg[i][j], 0, 0, 0);
            }
    }
    __syncthreads();  // staging LDS dead; safe to reuse as avl

    // epilogue: (a,v) from fp32 accs; write global av + LDS transpose copy
    const int r0row = (lane >> 4) * 4;
#pragma unroll
    for (int i = 0; i < 4; ++i) {
#pragma unroll
        for (int r = 0; r < 4; ++r) {
            const int row = wm + i * 16 + r0row + r;
#pragma unroll
            for (int j = 0; j < 4; ++j) {
                const int col = wn + j * 16 + fr;
                float h = acch[i][j][r];
                float g = accg[i][j][r];
                g = fminf(fmaxf(g, -30.f), 30.f);
                float e = __expf(-g);
                float z = 1.f / (1.f + e);
                float a = e * z;                      // 1 - sigmoid(g)
                float v = z * (fmaxf(h, 0.f) + 0.5f); // sigmoid(g)*(relu(h)+0.5)
                uint32_t pk = f2bf_bits(a) | (f2bf_bits(v) << 16);
                avl[row * 128 + col] = pk;
                av[(m0 + row) * 2048 + n0 + col] = pk;
            }
        }
    }
    __syncthreads();

    // in-block chunk-summary scan
    const int col = tid & 127;
    const int rlo = (tid >> 7) * 64;
    float Aa = 1.f, Vv = 0.f;
#pragma unroll 8
    for (int j = 0; j < 64; ++j) {
        uint32_t pk = avl[(rlo + j) * 128 + col];
        float a = bflo(pk), v = bfhi(pk);
        Vv = fmaf(a, Vv, v);
        Aa *= a;
    }
    __syncthreads();
    if (tid < 128) {
        avl[col] = __float_as_uint(Aa);
        avl[128 + col] = __float_as_uint(Vv);
    }
    __syncthreads();
    if (tid >= 128) {
        float Al = __uint_as_float(avl[col]);
        float Vl = __uint_as_float(avl[128 + col]);
        float At = Al * Aa;
        float Vt = fmaf(Aa, Vl, Vv);
        const int chunk = (int)(m0 >> 7);  // global chunk id = b*32+ch
        sumAV[(size_t)chunk * 2048 + n0 + col] = (float2){At, Vt};
    }
}

// ============================================================
// GEMM2 (R9): 256x128 m-tile. Staged bytes/FLOP improves 1.33x over
// 128x128 and barrier count per FLOP halves (staging-BW-bound regime).
// 4 waves; wave w handles rows [w*64, w*64+64) x all 128 cols.
// acc[4][8] = 128 VGPRs. grid (N/128=8, M/256=64).
// ============================================================
__global__ __launch_bounds__(256, 2) void gemm2_k(const u16* __restrict__ A,
                                                  const u16* __restrict__ Bt,
                                                  float* __restrict__ C) {
    const int N = DIMX, K = DIM_INNER;
    __shared__ alignas(16) u16 As[256 * 32];  // 16 KB
    __shared__ alignas(16) u16 Bs[128 * 32];  // 8 KB

    const int tid = threadIdx.x;
    const int lane = tid & 63;
    const int wave = tid >> 6;
    const int wm = wave * 64;              // wave's row offset in 256-row tile
    const size_t m0 = (size_t)blockIdx.y * 256;
    const size_t n0 = (size_t)blockIdx.x * 128;

    floatx4 acc[4][8];
#pragma unroll
    for (int i = 0; i < 4; ++i)
#pragma unroll
        for (int j = 0; j < 8; ++j) acc[i][j] = (floatx4){0.f, 0.f, 0.f, 0.f};

    const int srow = lane >> 2;
    const int scol = ((lane & 3) ^ ((srow >> 1) & 3)) * 8;
    const u16* Ag = A + (m0 + wave * 16 + srow) * K + scol;
    const u16* Bg = Bt + (n0 + wave * 16 + srow) * K + scol;
    u16* Asw = As + (wave * 16) * 32;
    u16* Bsw = Bs + (wave * 16) * 32;

    const int fr = lane & 15;
    const int kblk = lane >> 4;
    const int koff = (kblk ^ ((fr >> 1) & 3)) * 8;

    for (int k0 = 0; k0 < K; k0 += 32) {
        __syncthreads();
#pragma unroll
        for (int i = 0; i < 4; ++i)
            __builtin_amdgcn_global_load_lds(
                (const __attribute__((address_space(1))) uint32_t*)(const void*)(Ag + (size_t)i * 64 * K + k0),
                (__attribute__((address_space(3))) uint32_t*)(void*)(Asw + i * 64 * 32), 16, 0, 0);
#pragma unroll
        for (int i = 0; i < 2; ++i)
            __builtin_amdgcn_global_load_lds(
                (const __attribute__((address_space(1))) uint32_t*)(const void*)(Bg + (size_t)i * 64 * K + k0),
                (__attribute__((address_space(3))) uint32_t*)(void*)(Bsw + i * 64 * 32), 16, 0, 0);
        __syncthreads();

        short8 af[4], bf[8];
#pragma unroll
        for (int i = 0; i < 4; ++i)
            af[i] = *(const short8*)(As + (wm + i * 16 + fr) * 32 + koff);
#pragma unroll
        for (int j = 0; j < 8; ++j)
            bf[j] = *(const short8*)(Bs + (j * 16 + fr) * 32 + koff);
#pragma unroll
        for (int i = 0; i < 4; ++i)
#pragma unroll
            for (int j = 0; j < 8; ++j)
                acc[i][j] = __builtin_amdgcn_mfma_f32_16x16x32_bf16(af[i], bf[j], acc[i][j], 0, 0, 0);
    }

    const int r0row = (lane >> 4) * 4;
#pragma unroll
    for (int i = 0; i < 4; ++i)
#pragma unroll
        for (int r = 0; r < 4; ++r) {
            size_t row = m0 + wm + i * 16 + r0row + r;
#pragma unroll
            for (int j = 0; j < 8; ++j) {
                size_t col = n0 + j * 16 + fr;
                C[row * N + col] = acc[i][j][r];
            }
        }
}

// ============================================================
// Phase B: carry scan over 32 chunk summaries per (batch, channel) chain.
// ============================================================
__global__ __launch_bounds__(64) void scan_carry(const float2* __restrict__ sumAV,
                                                 float* __restrict__ carry) {
    const int g = blockIdx.x * 64 + threadIdx.x;  // 0..8191
    const int b = g >> 11, c = g & 2047;
    float h = 0.f;
#pragma unroll 8
    for (int ch = 0; ch < NCHUNK; ++ch) {
        float2 s = sumAV[(size_t)(b * NCHUNK + ch) * 2048 + c];
        carry[(size_t)(b * NCHUNK + ch) * 2048 + c] = h;
        h = fmaf(s.x, h, s.y);
    }
}

// ============================================================
// Phase C: replay chunk from packed (a,v), carry-in, emit h bf16.
// R9: batch-4 prefetch (4 x 8B loads in flight per thread).
// grid (4, NCHUNK, BATCH) x 256; thread -> 2 channels.
// ============================================================
__global__ __launch_bounds__(256) void scan_apply(const uint32_t* __restrict__ av,
                                                  const float* __restrict__ carry,
                                                  uint32_t* __restrict__ hbuf) {
    const int b = blockIdx.z, ch = blockIdx.y;
    const int c2 = blockIdx.x * 256 + threadIdx.x;  // channel-pair 0..1023
    const size_t rowbase = (size_t)b * SEQ + (size_t)ch * CLEN;
    const uint32_t* p = av + rowbase * 2048 + c2 * 2;
    uint32_t* q = hbuf + rowbase * 1024 + c2;
    const float2 cin = ((const float2*)carry)[(size_t)(b * NCHUNK + ch) * 1024 + c2];
    float h0 = cin.x, h1 = cin.y;

    uint2 buf[4];
#pragma unroll
    for (int t = 0; t < 4; ++t) buf[t] = *(const uint2*)(p + (size_t)t * 2048);

    for (int j0 = 0; j0 < CLEN; j0 += 4) {
        uint2 nxt[4];
        if (j0 + 4 < CLEN) {
#pragma unroll
            for (int t = 0; t < 4; ++t)
                nxt[t] = *(const uint2*)(p + (size_t)(j0 + 4 + t) * 2048);
        }
#pragma unroll
        for (int t = 0; t < 4; ++t) {
            float a0 = bflo(buf[t].x), v0 = bfhi(buf[t].x);
            float a1 = bflo(buf[t].y), v1 = bfhi(buf[t].y);
            h0 = fmaf(a0, h0, v0);
            h1 = fmaf(a1, h1, v1);
            q[(size_t)(j0 + t) * 1024] = f2bf_bits(h0) | (f2bf_bits(h1) << 16);
        }
#pragma unroll
        for (int t = 0; t < 4; ++t) buf[t] = nxt[t];
    }
}

// ============================================================
extern "C" void kernel_launch(void* const* d_in, const int* in_sizes, int n_in,
                              void* d_out, int out_size, void* d_ws, size_t ws_size,
                              hipStream_t stream) {
    const float* x = (const float*)d_in[0];     // [16384,1024]
    const float* Whg = (const float*)d_in[1];   // [1024,4096]
    const float* Wout = (const float*)d_in[2];  // [2048,1024]

    char* ws = (char*)d_ws;
    size_t off = 0;
    u16* xb = (u16*)(ws + off);        off += (size_t)M_TOTAL * DIMX * 2;          // 33.6 MB
    u16* whgt = (u16*)(ws + off);      off += (size_t)N_HG * DIMX * 2;             // 8.4 MB
    u16* woutt = (u16*)(ws + off);     off += (size_t)DIMX * DIM_INNER * 2;        // 4.2 MB
    uint32_t* av = (uint32_t*)(ws + off); off += (size_t)M_TOTAL * DIM_INNER * 4;  // 134.2 MB
    uint32_t* hbuf = (uint32_t*)(ws + off); off += (size_t)M_TOTAL * DIM_INNER * 2; // 67.1 MB
    float2* sumAV = (float2*)(ws + off); off += (size_t)BATCH * NCHUNK * DIM_INNER * 8; // 2.1 MB
    // carry (1 MB) aliases whgt: whgt dead after gemm1_k (stream-ordered).
    float* carry = (float*)whgt;

    // 1. fused prep
    prep<<<2048 + 1024 + 512, 256, 0, stream>>>(x, Whg, Wout, xb, whgt, woutt);

    // 2. GEMM1 fused: av + per-chunk summaries
    gemm1_k<<<dim3(16, 128), 256, 0, stream>>>(xb, whgt, av, sumAV);

    // 3. carry scan (chains of 32) + replay
    scan_carry<<<128, 64, 0, stream>>>(sumAV, carry);
    scan_apply<<<dim3(4, NCHUNK, BATCH), 256, 0, stream>>>(av, carry, hbuf);

    // 4. GEMM2: out = h @ Wout (fp32 out), 256x128 tiles
    gemm2_k<<<dim3(DIMX / 128, M_TOTAL / 256), 256, 0, stream>>>((const u16*)hbuf, woutt, (float*)d_out);
}